// Round 1
// baseline (859.005 us; speedup 1.0000x reference)
//
#include <hip/hip_runtime.h>

// ---------------------------------------------------------------------------
// GRU (B=256,S=512,F=128,H=64) + MLP(32768->512->256->100) + softmax, all fp32.
// Round 1: correctness-first fp32 vector implementation.
//   k_gemm_gx : gx = x @ W_x2h^T  (chunked over S in 4 pieces of 128)
//   k_scan    : sequential GRU scan, 1 batch per block (192 thr = 3 waves),
//               W_h2h rows live in VGPRs, h broadcast via v_readlane->SGPR.
//   k_fc1     : out1 += out @ W1^T  (64-way k-split, fp32 atomicAdd accum)
//   k_tail    : relu -> FC2 -> relu -> FC3 -> softmax -> d_out
// ---------------------------------------------------------------------------

constexpr int B = 256, S = 512, F = 128, H = 64, G = 192, C = 100;
constexpr int N1 = 512;
constexpr int SCHUNK = 128, NCHUNK = 4;

// workspace layout (float offsets)
constexpr size_t OFF_GX   = 0;                                   // B*SCHUNK*G
constexpr size_t OFF_OUT  = OFF_GX + (size_t)B * SCHUNK * G;     // B*S*H
constexpr size_t OFF_OUT1 = OFF_OUT + (size_t)B * S * H;         // B*N1
constexpr size_t OFF_H    = OFF_OUT1 + (size_t)B * N1;           // B*H

// ---------------------------------------------------------------------------
// GEMM1: gx[b][sl][g] = sum_f x[b, sc*128+sl, f] * Wx[g][f]
// block = one batch (128 rows), 256 threads, tile 128m x 192n, thread 8x12.
// LDS [k][m] / [k][n] with XOR swizzle ((k>>2)&7)<<2 on the column index.
// ---------------------------------------------------------------------------
__global__ __launch_bounds__(256, 1) void k_gemm_gx(const float* __restrict__ x,
                                                    const float* __restrict__ Wx,
                                                    float* __restrict__ gx, int sc) {
  __shared__ float xs[32 * 128];
  __shared__ float wsm[32 * 192];
  const int tid = threadIdx.x;
  const int b = blockIdx.x;
  const float* xrow = x + ((size_t)b * S + (size_t)sc * SCHUNK) * F;
  const int mt = tid & 15, nt = tid >> 4;
  float acc[8][12];
#pragma unroll
  for (int i = 0; i < 8; i++)
#pragma unroll
    for (int j = 0; j < 12; j++) acc[i][j] = 0.f;

  for (int kc = 0; kc < 4; kc++) {
    const int kbase = kc * 32;
#pragma unroll
    for (int i = 0; i < 4; i++) {
      int flat = tid + i * 256;  // 0..1023
      int row = flat >> 3;       // 0..127
      int k4 = flat & 7;
      float4 v = *(const float4*)(xrow + (size_t)row * F + kbase + k4 * 4);
      int sw = k4 << 2;
      xs[(k4 * 4 + 0) * 128 + (row ^ sw)] = v.x;
      xs[(k4 * 4 + 1) * 128 + (row ^ sw)] = v.y;
      xs[(k4 * 4 + 2) * 128 + (row ^ sw)] = v.z;
      xs[(k4 * 4 + 3) * 128 + (row ^ sw)] = v.w;
    }
#pragma unroll
    for (int i = 0; i < 6; i++) {
      int flat = tid + i * 256;  // 0..1535
      int row = flat >> 3;       // 0..191
      int k4 = flat & 7;
      float4 v = *(const float4*)(Wx + (size_t)row * F + kbase + k4 * 4);
      int sw = k4 << 2;
      wsm[(k4 * 4 + 0) * 192 + (row ^ sw)] = v.x;
      wsm[(k4 * 4 + 1) * 192 + (row ^ sw)] = v.y;
      wsm[(k4 * 4 + 2) * 192 + (row ^ sw)] = v.z;
      wsm[(k4 * 4 + 3) * 192 + (row ^ sw)] = v.w;
    }
    __syncthreads();
#pragma unroll 8
    for (int k = 0; k < 32; k++) {
      int sw = ((k >> 2) & 7) << 2;
      float4 a0 = *(const float4*)(xs + k * 128 + ((mt * 4) ^ sw));
      float4 a1 = *(const float4*)(xs + k * 128 + ((mt * 4 + 64) ^ sw));
      float4 b0 = *(const float4*)(wsm + k * 192 + ((nt * 4) ^ sw));
      float4 b1 = *(const float4*)(wsm + k * 192 + ((nt * 4 + 64) ^ sw));
      float4 b2 = *(const float4*)(wsm + k * 192 + ((nt * 4 + 128) ^ sw));
      float am[8] = {a0.x, a0.y, a0.z, a0.w, a1.x, a1.y, a1.z, a1.w};
      float bn[12] = {b0.x, b0.y, b0.z, b0.w, b1.x, b1.y, b1.z, b1.w,
                      b2.x, b2.y, b2.z, b2.w};
#pragma unroll
      for (int i = 0; i < 8; i++)
#pragma unroll
        for (int j = 0; j < 12; j++) acc[i][j] = fmaf(am[i], bn[j], acc[i][j]);
    }
    __syncthreads();
  }
#pragma unroll
  for (int q = 0; q < 2; q++)
#pragma unroll
    for (int i = 0; i < 4; i++) {
      int m = q * 64 + mt * 4 + i;
      float* dst = gx + ((size_t)b * SCHUNK + m) * G + nt * 4;
#pragma unroll
      for (int t = 0; t < 3; t++) {
        float4 v = make_float4(acc[q * 4 + i][t * 4 + 0], acc[q * 4 + i][t * 4 + 1],
                               acc[q * 4 + i][t * 4 + 2], acc[q * 4 + i][t * 4 + 3]);
        *(float4*)(dst + t * 64) = v;
      }
    }
}

// ---------------------------------------------------------------------------
// GRU scan: block = one batch, 192 threads (3 waves: g = tid in [0,192)).
// Lane g keeps W_h2h row g in 64 VGPRs for the whole kernel.
// h broadcast per step via v_readlane into SGPRs (no LDS broadcast storm).
// wave0: i_r+h_r ; wave1: i_i+h_i ; wave2: i_n , h_n (kept separate).
// ---------------------------------------------------------------------------
__global__ __launch_bounds__(192, 1) void k_scan(const float* __restrict__ gx,
                                                 const float* __restrict__ Wh,
                                                 float* __restrict__ out,
                                                 float* __restrict__ hst, int sc) {
  __shared__ float h_s[64], s1[64], ghn[64], gxn[64];
  const int tid = threadIdx.x;
  const int w = tid >> 6, l = tid & 63;
  const int b = blockIdx.x;
  float W[64];
#pragma unroll
  for (int k = 0; k < 64; k += 4) {
    float4 v = *(const float4*)(Wh + (size_t)tid * H + k);
    W[k] = v.x; W[k + 1] = v.y; W[k + 2] = v.z; W[k + 3] = v.w;
  }
  float h_own = 0.f, hv = 0.f;
  if (sc != 0) {
    hv = hst[b * H + l];
    if (w == 0) h_own = hv;
  }
  const float* gxb = gx + (size_t)b * SCHUNK * G + tid;
  float g_c = gxb[0];
  float g_n1 = gxb[G];
  float* outb = out + (size_t)b * (S * H) + (size_t)(sc * SCHUNK) * H + l;

  for (int sl = 0; sl < SCHUNK; sl++) {
    int pf = (sl + 2 < SCHUNK) ? sl + 2 : SCHUNK - 1;
    float g_n2 = gxb[(size_t)pf * G];  // depth-2 prefetch (L3-latency cover)
    float acc0 = 0.f, acc1 = 0.f, acc2 = 0.f, acc3 = 0.f;
#pragma unroll
    for (int k = 0; k < 64; k += 4) {
      float h0 = __int_as_float(__builtin_amdgcn_readlane(__float_as_int(hv), k + 0));
      float h1 = __int_as_float(__builtin_amdgcn_readlane(__float_as_int(hv), k + 1));
      float h2 = __int_as_float(__builtin_amdgcn_readlane(__float_as_int(hv), k + 2));
      float h3 = __int_as_float(__builtin_amdgcn_readlane(__float_as_int(hv), k + 3));
      acc0 = fmaf(h0, W[k + 0], acc0);
      acc1 = fmaf(h1, W[k + 1], acc1);
      acc2 = fmaf(h2, W[k + 2], acc2);
      acc3 = fmaf(h3, W[k + 3], acc3);
    }
    float gh = (acc0 + acc1) + (acc2 + acc3);
    if (w == 1) {
      s1[l] = gh + g_c;
    } else if (w == 2) {
      ghn[l] = gh;
      gxn[l] = g_c;
    }
    __syncthreads();
    if (w == 0) {
      float r = 1.f / (1.f + __expf(-(gh + g_c)));
      float ii = 1.f / (1.f + __expf(-s1[l]));
      float na = gxn[l] + r * ghn[l];
      float e = __expf(-2.f * fabsf(na));
      float t = (1.f - e) / (1.f + e);
      t = (na < 0.f) ? -t : t;
      h_own = t + ii * (h_own - t);
      h_s[l] = h_own;
      outb[(size_t)sl * H] = h_own;
    }
    __syncthreads();
    hv = h_s[l];
    g_c = g_n1;
    g_n1 = g_n2;
  }
  if (w == 0) hst[b * H + l] = h_own;
}

// ---------------------------------------------------------------------------
// FC1: out1[m][n] += sum_k out[m][k] * W1[n][k], m=256 (all batches), n-tile=128,
// 64-way k-split (kchunk=512), fp32 atomicAdd accumulation into out1.
// 256 threads, thread tile 16m x 8n. Same XOR swizzle as above.
// ---------------------------------------------------------------------------
__global__ __launch_bounds__(256, 1) void k_fc1(const float* __restrict__ A,
                                                const float* __restrict__ W1,
                                                float* __restrict__ out1) {
  __shared__ float As[32 * 256];
  __shared__ float Bs[32 * 128];
  const int tid = threadIdx.x;
  const int ntile = blockIdx.x & 3;
  const int ks = blockIdx.x >> 2;
  const int k0b = ks * 512;
  const int mt = tid & 15, nt = tid >> 4;
  float acc[16][8];
#pragma unroll
  for (int i = 0; i < 16; i++)
#pragma unroll
    for (int j = 0; j < 8; j++) acc[i][j] = 0.f;

  for (int kc = 0; kc < 16; kc++) {
    const int k0 = k0b + kc * 32;
#pragma unroll
    for (int i = 0; i < 8; i++) {
      int flat = tid + i * 256;  // 0..2047
      int row = flat >> 3;       // 0..255
      int k4 = flat & 7;
      float4 v = *(const float4*)(A + (size_t)row * (S * H) + k0 + k4 * 4);
      int sw = k4 << 2;
      As[(k4 * 4 + 0) * 256 + (row ^ sw)] = v.x;
      As[(k4 * 4 + 1) * 256 + (row ^ sw)] = v.y;
      As[(k4 * 4 + 2) * 256 + (row ^ sw)] = v.z;
      As[(k4 * 4 + 3) * 256 + (row ^ sw)] = v.w;
    }
#pragma unroll
    for (int i = 0; i < 4; i++) {
      int flat = tid + i * 256;  // 0..1023
      int row = flat >> 3;       // 0..127
      int k4 = flat & 7;
      float4 v = *(const float4*)(W1 + (size_t)(ntile * 128 + row) * (S * H) + k0 + k4 * 4);
      int sw = k4 << 2;
      Bs[(k4 * 4 + 0) * 128 + (row ^ sw)] = v.x;
      Bs[(k4 * 4 + 1) * 128 + (row ^ sw)] = v.y;
      Bs[(k4 * 4 + 2) * 128 + (row ^ sw)] = v.z;
      Bs[(k4 * 4 + 3) * 128 + (row ^ sw)] = v.w;
    }
    __syncthreads();
#pragma unroll 4
    for (int k = 0; k < 32; k++) {
      int sw = ((k >> 2) & 7) << 2;
      float4 a0 = *(const float4*)(As + k * 256 + ((mt * 4) ^ sw));
      float4 a1 = *(const float4*)(As + k * 256 + ((mt * 4 + 64) ^ sw));
      float4 a2 = *(const float4*)(As + k * 256 + ((mt * 4 + 128) ^ sw));
      float4 a3 = *(const float4*)(As + k * 256 + ((mt * 4 + 192) ^ sw));
      float4 b0 = *(const float4*)(Bs + k * 128 + ((nt * 4) ^ sw));
      float4 b1 = *(const float4*)(Bs + k * 128 + ((nt * 4 + 64) ^ sw));
      float am[16] = {a0.x, a0.y, a0.z, a0.w, a1.x, a1.y, a1.z, a1.w,
                      a2.x, a2.y, a2.z, a2.w, a3.x, a3.y, a3.z, a3.w};
      float bn[8] = {b0.x, b0.y, b0.z, b0.w, b1.x, b1.y, b1.z, b1.w};
#pragma unroll
      for (int i = 0; i < 16; i++)
#pragma unroll
        for (int j = 0; j < 8; j++) acc[i][j] = fmaf(am[i], bn[j], acc[i][j]);
    }
    __syncthreads();
  }
#pragma unroll
  for (int q = 0; q < 4; q++)
#pragma unroll
    for (int i = 0; i < 4; i++) {
      int m = q * 64 + mt * 4 + i;
      float* dst = out1 + (size_t)m * N1 + ntile * 128 + nt * 4;
#pragma unroll
      for (int hh = 0; hh < 2; hh++)
#pragma unroll
        for (int j = 0; j < 4; j++)
          atomicAdd(dst + hh * 64 + j, acc[q * 4 + i][hh * 4 + j]);
    }
}

// ---------------------------------------------------------------------------
// Tail: relu(out1 row) -> FC2+relu -> FC3 -> softmax. One block per batch.
// ---------------------------------------------------------------------------
__global__ __launch_bounds__(256, 1) void k_tail(const float* __restrict__ out1,
                                                 const float* __restrict__ W2,
                                                 const float* __restrict__ W3,
                                                 float* __restrict__ dout) {
  __shared__ float o1[N1];
  __shared__ float o2[256];
  __shared__ float lg[128];
  const int tid = threadIdx.x;
  const int b = blockIdx.x;
  {
    float2 v = *(const float2*)(out1 + (size_t)b * N1 + tid * 2);
    o1[tid * 2 + 0] = fmaxf(v.x, 0.f);
    o1[tid * 2 + 1] = fmaxf(v.y, 0.f);
  }
  __syncthreads();
  {
    const float* w2r = W2 + (size_t)tid * N1;
    float a0 = 0, a1 = 0, a2 = 0, a3 = 0;
#pragma unroll 4
    for (int k = 0; k < N1; k += 4) {
      float4 ov = *(const float4*)(o1 + k);
      float4 wv = *(const float4*)(w2r + k);
      a0 = fmaf(ov.x, wv.x, a0);
      a1 = fmaf(ov.y, wv.y, a1);
      a2 = fmaf(ov.z, wv.z, a2);
      a3 = fmaf(ov.w, wv.w, a3);
    }
    o2[tid] = fmaxf((a0 + a1) + (a2 + a3), 0.f);
  }
  __syncthreads();
  if (tid < C) {
    const float* w3r = W3 + (size_t)tid * 256;
    float a0 = 0, a1 = 0, a2 = 0, a3 = 0;
#pragma unroll 4
    for (int k = 0; k < 256; k += 4) {
      float4 ov = *(const float4*)(o2 + k);
      float4 wv = *(const float4*)(w3r + k);
      a0 = fmaf(ov.x, wv.x, a0);
      a1 = fmaf(ov.y, wv.y, a1);
      a2 = fmaf(ov.z, wv.z, a2);
      a3 = fmaf(ov.w, wv.w, a3);
    }
    lg[tid] = (a0 + a1) + (a2 + a3);
  }
  __syncthreads();
  if (tid < 64) {
    float v0 = lg[tid];
    float v1 = (tid + 64 < C) ? lg[tid + 64] : -3.0e38f;
    float m = fmaxf(v0, v1);
#pragma unroll
    for (int off = 32; off > 0; off >>= 1) m = fmaxf(m, __shfl_xor(m, off, 64));
    float e0 = __expf(v0 - m);
    float e1 = (tid + 64 < C) ? __expf(v1 - m) : 0.f;
    float ssum = e0 + e1;
#pragma unroll
    for (int off = 32; off > 0; off >>= 1) ssum += __shfl_xor(ssum, off, 64);
    float inv = 1.f / ssum;
    dout[(size_t)b * C + tid] = e0 * inv;
    if (tid + 64 < C) dout[(size_t)b * C + tid + 64] = e1 * inv;
  }
}

// ---------------------------------------------------------------------------
extern "C" void kernel_launch(void* const* d_in, const int* in_sizes, int n_in,
                              void* d_out, int out_size, void* d_ws, size_t ws_size,
                              hipStream_t stream) {
  (void)in_sizes; (void)n_in; (void)out_size; (void)ws_size;
  const float* x = (const float*)d_in[0];
  const float* Wx = (const float*)d_in[1];
  const float* Wh = (const float*)d_in[2];
  const float* W1 = (const float*)d_in[3];
  const float* W2 = (const float*)d_in[4];
  const float* W3 = (const float*)d_in[5];
  float* ws = (float*)d_ws;
  float* gx = ws + OFF_GX;
  float* gout = ws + OFF_OUT;
  float* out1 = ws + OFF_OUT1;
  float* hst = ws + OFF_H;

  hipMemsetAsync(out1, 0, (size_t)B * N1 * sizeof(float), stream);
  for (int sc = 0; sc < NCHUNK; sc++) {
    k_gemm_gx<<<dim3(B), dim3(256), 0, stream>>>(x, Wx, gx, sc);
    k_scan<<<dim3(B), dim3(192), 0, stream>>>(gx, Wh, gout, hst, sc);
  }
  k_fc1<<<dim3(256), dim3(256), 0, stream>>>(gout, W1, out1);
  k_tail<<<dim3(B), dim3(256), 0, stream>>>(out1, W2, W3, (float*)d_out);
}

// Round 2
// 630.494 us; speedup vs baseline: 1.3624x; 1.3624x over previous
//
#include <hip/hip_runtime.h>

// ---------------------------------------------------------------------------
// GRU (B=256,S=512,F=128,H=64) + MLP(32768->512->256->100) + softmax.
// Round 2:
//   k_gemm_gx : unchanged fp32 tiled GEMM (gx = x @ W_x2h^T), S chunked by 128.
//   k_scan    : 4-wave k-split-by-4 GRU scan; quad ds_swizzle reduce; fast
//               exp2/rcp gates; raw barriers (no vmcnt drain); emits h as
//               bf16 hi/lo planes (feeds fc1 directly).
//   k_fc1     : 3-pass split-bf16 MFMA GEMM (A_hi*W_hi + A_lo*W_hi + A_hi*W_lo),
//               256x128 tiles, runtime k-split -> psum (no atomics).
//   k_red     : psum reduction -> out1 (fp32).
//   k_tail    : relu -> FC2 -> relu -> FC3 -> softmax -> d_out.
// ---------------------------------------------------------------------------

constexpr int B = 256, S = 512, F = 128, H = 64, G = 192, C = 100;
constexpr int N1 = 512;
constexpr int SCHUNK = 128, NCHUNK = 4;
constexpr int K1 = S * H;  // 32768

typedef __attribute__((ext_vector_type(8))) __bf16 bf16x8;
typedef __attribute__((ext_vector_type(4))) float f32x4;

__device__ __forceinline__ unsigned short f2bf(float f) {
  unsigned int u = __float_as_uint(f);
  unsigned int r = (u + 0x7FFFu + ((u >> 16) & 1u)) >> 16;
  return (unsigned short)r;
}
__device__ __forceinline__ float bf2f(unsigned short s) {
  return __uint_as_float((unsigned int)s << 16);
}
__device__ __forceinline__ float sigm_fast(float x) {
  float e = __builtin_amdgcn_exp2f(-1.4426950408889634f * x);
  return __builtin_amdgcn_rcpf(1.f + e);
}
__device__ __forceinline__ float tanh_fast(float x) {
  float e = __builtin_amdgcn_exp2f(2.8853900817779268f * x);  // e^{2x}
  return 1.f - 2.f * __builtin_amdgcn_rcpf(1.f + e);
}
__device__ __forceinline__ float swz_x1(float v) {
  return __int_as_float(__builtin_amdgcn_ds_swizzle(__float_as_int(v), 0x041F));
}
__device__ __forceinline__ float swz_x2(float v) {
  return __int_as_float(__builtin_amdgcn_ds_swizzle(__float_as_int(v), 0x081F));
}

// ---------------------------------------------------------------------------
// GEMM1: gx[b][sl][g] = sum_f x[b, sc*128+sl, f] * Wx[g][f]   (unchanged)
// ---------------------------------------------------------------------------
__global__ __launch_bounds__(256, 1) void k_gemm_gx(const float* __restrict__ x,
                                                    const float* __restrict__ Wx,
                                                    float* __restrict__ gx, int sc) {
  __shared__ float xs[32 * 128];
  __shared__ float wsm[32 * 192];
  const int tid = threadIdx.x;
  const int b = blockIdx.x;
  const float* xrow = x + ((size_t)b * S + (size_t)sc * SCHUNK) * F;
  const int mt = tid & 15, nt = tid >> 4;
  float acc[8][12];
#pragma unroll
  for (int i = 0; i < 8; i++)
#pragma unroll
    for (int j = 0; j < 12; j++) acc[i][j] = 0.f;

  for (int kc = 0; kc < 4; kc++) {
    const int kbase = kc * 32;
#pragma unroll
    for (int i = 0; i < 4; i++) {
      int flat = tid + i * 256;
      int row = flat >> 3;
      int k4 = flat & 7;
      float4 v = *(const float4*)(xrow + (size_t)row * F + kbase + k4 * 4);
      int sw = k4 << 2;
      xs[(k4 * 4 + 0) * 128 + (row ^ sw)] = v.x;
      xs[(k4 * 4 + 1) * 128 + (row ^ sw)] = v.y;
      xs[(k4 * 4 + 2) * 128 + (row ^ sw)] = v.z;
      xs[(k4 * 4 + 3) * 128 + (row ^ sw)] = v.w;
    }
#pragma unroll
    for (int i = 0; i < 6; i++) {
      int flat = tid + i * 256;
      int row = flat >> 3;
      int k4 = flat & 7;
      float4 v = *(const float4*)(Wx + (size_t)row * F + kbase + k4 * 4);
      int sw = k4 << 2;
      wsm[(k4 * 4 + 0) * 192 + (row ^ sw)] = v.x;
      wsm[(k4 * 4 + 1) * 192 + (row ^ sw)] = v.y;
      wsm[(k4 * 4 + 2) * 192 + (row ^ sw)] = v.z;
      wsm[(k4 * 4 + 3) * 192 + (row ^ sw)] = v.w;
    }
    __syncthreads();
#pragma unroll 8
    for (int k = 0; k < 32; k++) {
      int sw = ((k >> 2) & 7) << 2;
      float4 a0 = *(const float4*)(xs + k * 128 + ((mt * 4) ^ sw));
      float4 a1 = *(const float4*)(xs + k * 128 + ((mt * 4 + 64) ^ sw));
      float4 b0 = *(const float4*)(wsm + k * 192 + ((nt * 4) ^ sw));
      float4 b1 = *(const float4*)(wsm + k * 192 + ((nt * 4 + 64) ^ sw));
      float4 b2 = *(const float4*)(wsm + k * 192 + ((nt * 4 + 128) ^ sw));
      float am[8] = {a0.x, a0.y, a0.z, a0.w, a1.x, a1.y, a1.z, a1.w};
      float bn[12] = {b0.x, b0.y, b0.z, b0.w, b1.x, b1.y, b1.z, b1.w,
                      b2.x, b2.y, b2.z, b2.w};
#pragma unroll
      for (int i = 0; i < 8; i++)
#pragma unroll
        for (int j = 0; j < 12; j++) acc[i][j] = fmaf(am[i], bn[j], acc[i][j]);
    }
    __syncthreads();
  }
#pragma unroll
  for (int qq = 0; qq < 2; qq++)
#pragma unroll
    for (int i = 0; i < 4; i++) {
      int m = qq * 64 + mt * 4 + i;
      float* dst = gx + ((size_t)b * SCHUNK + m) * G + nt * 4;
#pragma unroll
      for (int t3 = 0; t3 < 3; t3++) {
        float4 v = make_float4(acc[qq * 4 + i][t3 * 4 + 0], acc[qq * 4 + i][t3 * 4 + 1],
                               acc[qq * 4 + i][t3 * 4 + 2], acc[qq * 4 + i][t3 * 4 + 3]);
        *(float4*)(dst + t3 * 64) = v;
      }
    }
}

// ---------------------------------------------------------------------------
// GRU scan v2: 256 threads (4 waves). Thread (w,l): output col j=16w+(l>>2),
// k-slice q=l&3 (16 k each). Quad butterfly via ds_swizzle. All lanes compute
// gates redundantly; q==0 lanes commit h and bf16 hi/lo output planes.
// Raw barriers: s_waitcnt lgkmcnt(0); s_barrier  (no vmcnt drain).
// ---------------------------------------------------------------------------
__global__ __launch_bounds__(256, 1) void k_scan(const float* __restrict__ gx,
                                                 const float* __restrict__ Wh,
                                                 unsigned short* __restrict__ outh,
                                                 unsigned short* __restrict__ outl,
                                                 float* __restrict__ hst, int sc) {
  __shared__ float h_s[64];
  const int t = threadIdx.x;
  const int w = t >> 6, l = t & 63;
  const int j = (w << 4) | (l >> 2);
  const int q = l & 3;
  const int b = blockIdx.x;

  float Wr[16], Wi[16], Wn[16];
  {
    const float* p0 = Wh + (size_t)j * H + q * 16;
    const float* p1 = Wh + (size_t)(64 + j) * H + q * 16;
    const float* p2 = Wh + (size_t)(128 + j) * H + q * 16;
#pragma unroll
    for (int c = 0; c < 4; c++) {
      float4 v0 = *(const float4*)(p0 + c * 4);
      float4 v1 = *(const float4*)(p1 + c * 4);
      float4 v2 = *(const float4*)(p2 + c * 4);
      Wr[c * 4 + 0] = v0.x; Wr[c * 4 + 1] = v0.y; Wr[c * 4 + 2] = v0.z; Wr[c * 4 + 3] = v0.w;
      Wi[c * 4 + 0] = v1.x; Wi[c * 4 + 1] = v1.y; Wi[c * 4 + 2] = v1.z; Wi[c * 4 + 3] = v1.w;
      Wn[c * 4 + 0] = v2.x; Wn[c * 4 + 1] = v2.y; Wn[c * 4 + 2] = v2.z; Wn[c * 4 + 3] = v2.w;
    }
  }
  float h_own;
  if (sc == 0) {
    h_own = 0.f;
    if (t < 64) h_s[t] = 0.f;
  } else {
    h_own = hst[b * H + j];
    if (t < 64) h_s[t] = hst[b * H + t];
  }
  asm volatile("s_waitcnt lgkmcnt(0)\n\ts_barrier" ::: "memory");

  const float* gxb = gx + (size_t)b * SCHUNK * G;
  float gr = gxb[j], gi = gxb[64 + j], gn = gxb[128 + j];
  unsigned short* poh = outh + (size_t)b * K1 + (size_t)sc * SCHUNK * H + j;
  unsigned short* pol = outl + (size_t)b * K1 + (size_t)sc * SCHUNK * H + j;

  for (int sl = 0; sl < SCHUNK; sl++) {
    float4 ha = *(const float4*)&h_s[q * 16 + 0];
    float4 hb = *(const float4*)&h_s[q * 16 + 4];
    float4 hc = *(const float4*)&h_s[q * 16 + 8];
    float4 hd = *(const float4*)&h_s[q * 16 + 12];
    int np = (sl + 1 < SCHUNK) ? sl + 1 : sl;
    const float* gp = gxb + (size_t)np * G;
    float grn = gp[j], gin = gp[64 + j], gnn = gp[128 + j];
    // reads of h_s complete, then barrier (no vmcnt drain)
    asm volatile("s_waitcnt lgkmcnt(0)\n\ts_barrier" ::: "memory");

    float ar, ai, an;
    ar = Wr[0] * ha.x; ai = Wi[0] * ha.x; an = Wn[0] * ha.x;
    ar = fmaf(Wr[1], ha.y, ar); ai = fmaf(Wi[1], ha.y, ai); an = fmaf(Wn[1], ha.y, an);
    ar = fmaf(Wr[2], ha.z, ar); ai = fmaf(Wi[2], ha.z, ai); an = fmaf(Wn[2], ha.z, an);
    ar = fmaf(Wr[3], ha.w, ar); ai = fmaf(Wi[3], ha.w, ai); an = fmaf(Wn[3], ha.w, an);
    ar = fmaf(Wr[4], hb.x, ar); ai = fmaf(Wi[4], hb.x, ai); an = fmaf(Wn[4], hb.x, an);
    ar = fmaf(Wr[5], hb.y, ar); ai = fmaf(Wi[5], hb.y, ai); an = fmaf(Wn[5], hb.y, an);
    ar = fmaf(Wr[6], hb.z, ar); ai = fmaf(Wi[6], hb.z, ai); an = fmaf(Wn[6], hb.z, an);
    ar = fmaf(Wr[7], hb.w, ar); ai = fmaf(Wi[7], hb.w, ai); an = fmaf(Wn[7], hb.w, an);
    ar = fmaf(Wr[8], hc.x, ar); ai = fmaf(Wi[8], hc.x, ai); an = fmaf(Wn[8], hc.x, an);
    ar = fmaf(Wr[9], hc.y, ar); ai = fmaf(Wi[9], hc.y, ai); an = fmaf(Wn[9], hc.y, an);
    ar = fmaf(Wr[10], hc.z, ar); ai = fmaf(Wi[10], hc.z, ai); an = fmaf(Wn[10], hc.z, an);
    ar = fmaf(Wr[11], hc.w, ar); ai = fmaf(Wi[11], hc.w, ai); an = fmaf(Wn[11], hc.w, an);
    ar = fmaf(Wr[12], hd.x, ar); ai = fmaf(Wi[12], hd.x, ai); an = fmaf(Wn[12], hd.x, an);
    ar = fmaf(Wr[13], hd.y, ar); ai = fmaf(Wi[13], hd.y, ai); an = fmaf(Wn[13], hd.y, an);
    ar = fmaf(Wr[14], hd.z, ar); ai = fmaf(Wi[14], hd.z, ai); an = fmaf(Wn[14], hd.z, an);
    ar = fmaf(Wr[15], hd.w, ar); ai = fmaf(Wi[15], hd.w, ai); an = fmaf(Wn[15], hd.w, an);

    ar += swz_x1(ar); ar += swz_x2(ar);
    ai += swz_x1(ai); ai += swz_x2(ai);
    an += swz_x1(an); an += swz_x2(an);

    float rr = sigm_fast(ar + gr);
    float ii = sigm_fast(ai + gi);
    float na = gn + rr * an;
    float th = tanh_fast(na);
    h_own = th + ii * (h_own - th);

    if (q == 0) {
      h_s[j] = h_own;
      unsigned short hh = f2bf(h_own);
      unsigned short hl = f2bf(h_own - bf2f(hh));
      poh[(size_t)sl * H] = hh;
      pol[(size_t)sl * H] = hl;
    }
    gr = grn; gi = gin; gn = gnn;
    // h_s write visible before next iteration's reads
    asm volatile("s_waitcnt lgkmcnt(0)\n\ts_barrier" ::: "memory");
  }
  if (q == 0) hst[b * H + j] = h_own;
}

// ---------------------------------------------------------------------------
// FC1 (MFMA): psum[ks][m][n] = sum_{k in chunk ks} A[m][k]*W1[n][k]
// A given as bf16 hi/lo planes; W1 converted in-kernel. 3-pass split-bf16.
// Block: 256 thr (4 waves, 2x2), tile M=256 x N=128, BK=32.
// LDS slot swizzle: 16B slot sq = q ^ (row&3)  -> <=2-way conflicts (free).
// ---------------------------------------------------------------------------
__global__ __launch_bounds__(256, 1) void k_fc1(const unsigned short* __restrict__ Ahp,
                                                const unsigned short* __restrict__ Alp,
                                                const float* __restrict__ W1,
                                                float* __restrict__ psum, int KCH) {
  __shared__ unsigned short Ah[256 * 32];
  __shared__ unsigned short Al[256 * 32];
  __shared__ unsigned short Bh[128 * 32];
  __shared__ unsigned short Bl[128 * 32];
  const int t = threadIdx.x;
  const int ntile = blockIdx.x & 3;
  const int ks = blockIdx.x >> 2;
  const int k0b = ks * KCH;
  const int w = t >> 6, l = t & 63;
  const int wm = w >> 1, wn = w & 1;

  f32x4 acc[8][4] = {};

  const int br = t >> 1, bhh = t & 1;
  const float* bsrc = W1 + (size_t)(ntile * 128 + br) * K1 + bhh * 16;
  const int nkc = KCH >> 5;

  for (int kc = 0; kc < nkc; kc++) {
    const int k0 = k0b + kc * 32;
    // ---- stage A hi/lo (pure copy, swizzled content placement) ----
#pragma unroll
    for (int i = 0; i < 4; i++) {
      int slot = t + i * 256;  // 0..1023
      int row = slot >> 2, sq = slot & 3;
      int cq = sq ^ (row & 3);
      const uint4* sh = (const uint4*)(Ahp + (size_t)row * K1 + k0 + cq * 8);
      const uint4* sl2 = (const uint4*)(Alp + (size_t)row * K1 + k0 + cq * 8);
      *(uint4*)&Ah[row * 32 + sq * 8] = *sh;
      *(uint4*)&Al[row * 32 + sq * 8] = *sl2;
    }
    // ---- stage B: load fp32, split to bf16 hi/lo ----
    {
      const float* sp = bsrc + k0;
      float fv[16];
#pragma unroll
      for (int c = 0; c < 4; c++) {
        float4 v = *(const float4*)(sp + c * 4);
        fv[c * 4 + 0] = v.x; fv[c * 4 + 1] = v.y; fv[c * 4 + 2] = v.z; fv[c * 4 + 3] = v.w;
      }
      unsigned short hi[16], lo[16];
#pragma unroll
      for (int e = 0; e < 16; e++) {
        hi[e] = f2bf(fv[e]);
        lo[e] = f2bf(fv[e] - bf2f(hi[e]));
      }
#pragma unroll
      for (int half = 0; half < 2; half++) {
        int cq = bhh * 2 + half;           // content chunk
        int sq = cq ^ (br & 3);            // slot
        unsigned short* dh = &Bh[br * 32 + sq * 8];
        unsigned short* dl = &Bl[br * 32 + sq * 8];
#pragma unroll
        for (int e = 0; e < 8; e++) {
          dh[e] = hi[half * 8 + e];
          dl[e] = lo[half * 8 + e];
        }
      }
    }
    __syncthreads();
    // ---- fragments + MFMA (3 passes) ----
    bf16x8 bhf[4], blf[4];
#pragma unroll
    for (int nf = 0; nf < 4; nf++) {
      int rowb = wn * 64 + nf * 16 + (l & 15);
      int sq = (l >> 4) ^ (rowb & 3);
      bhf[nf] = *(const bf16x8*)&Bh[rowb * 32 + sq * 8];
      blf[nf] = *(const bf16x8*)&Bl[rowb * 32 + sq * 8];
    }
#pragma unroll
    for (int mf = 0; mf < 8; mf++) {
      int rowa = wm * 128 + mf * 16 + (l & 15);
      int sq = (l >> 4) ^ (rowa & 3);
      bf16x8 ah = *(const bf16x8*)&Ah[rowa * 32 + sq * 8];
      bf16x8 al = *(const bf16x8*)&Al[rowa * 32 + sq * 8];
#pragma unroll
      for (int nf = 0; nf < 4; nf++) {
        acc[mf][nf] = __builtin_amdgcn_mfma_f32_16x16x32_bf16(ah, bhf[nf], acc[mf][nf], 0, 0, 0);
        acc[mf][nf] = __builtin_amdgcn_mfma_f32_16x16x32_bf16(al, bhf[nf], acc[mf][nf], 0, 0, 0);
        acc[mf][nf] = __builtin_amdgcn_mfma_f32_16x16x32_bf16(ah, blf[nf], acc[mf][nf], 0, 0, 0);
      }
    }
    __syncthreads();
  }
  // ---- store partial tile: D row=(l>>4)*4+reg (A row), col=l&15 (W row) ----
#pragma unroll
  for (int mf = 0; mf < 8; mf++) {
#pragma unroll
    for (int nf = 0; nf < 4; nf++) {
      int m = wm * 128 + mf * 16 + (l >> 4) * 4;
      int n = ntile * 128 + wn * 64 + nf * 16 + (l & 15);
      float* dst = psum + ((size_t)ks * 256 + m) * N1 + n;
#pragma unroll
      for (int r = 0; r < 4; r++) dst[(size_t)r * N1] = acc[mf][nf][r];
    }
  }
}

// ---------------------------------------------------------------------------
// Reduce psum over KS chunks -> out1
// ---------------------------------------------------------------------------
__global__ void k_red(const float* __restrict__ psum, float* __restrict__ out1, int KS) {
  int i = (blockIdx.x * 256 + threadIdx.x) * 4;
  float4 s = make_float4(0.f, 0.f, 0.f, 0.f);
  for (int ks = 0; ks < KS; ks++) {
    float4 v = *(const float4*)(psum + (size_t)ks * (B * N1) + i);
    s.x += v.x; s.y += v.y; s.z += v.z; s.w += v.w;
  }
  *(float4*)(out1 + i) = s;
}

// ---------------------------------------------------------------------------
// Tail: relu(out1 row) -> FC2+relu -> FC3 -> softmax (unchanged)
// ---------------------------------------------------------------------------
__global__ __launch_bounds__(256, 1) void k_tail(const float* __restrict__ out1,
                                                 const float* __restrict__ W2,
                                                 const float* __restrict__ W3,
                                                 float* __restrict__ dout) {
  __shared__ float o1[N1];
  __shared__ float o2[256];
  __shared__ float lg[128];
  const int tid = threadIdx.x;
  const int b = blockIdx.x;
  {
    float2 v = *(const float2*)(out1 + (size_t)b * N1 + tid * 2);
    o1[tid * 2 + 0] = fmaxf(v.x, 0.f);
    o1[tid * 2 + 1] = fmaxf(v.y, 0.f);
  }
  __syncthreads();
  {
    const float* w2r = W2 + (size_t)tid * N1;
    float a0 = 0, a1 = 0, a2 = 0, a3 = 0;
#pragma unroll 4
    for (int k = 0; k < N1; k += 4) {
      float4 ov = *(const float4*)(o1 + k);
      float4 wv = *(const float4*)(w2r + k);
      a0 = fmaf(ov.x, wv.x, a0);
      a1 = fmaf(ov.y, wv.y, a1);
      a2 = fmaf(ov.z, wv.z, a2);
      a3 = fmaf(ov.w, wv.w, a3);
    }
    o2[tid] = fmaxf((a0 + a1) + (a2 + a3), 0.f);
  }
  __syncthreads();
  if (tid < C) {
    const float* w3r = W3 + (size_t)tid * 256;
    float a0 = 0, a1 = 0, a2 = 0, a3 = 0;
#pragma unroll 4
    for (int k = 0; k < 256; k += 4) {
      float4 ov = *(const float4*)(o2 + k);
      float4 wv = *(const float4*)(w3r + k);
      a0 = fmaf(ov.x, wv.x, a0);
      a1 = fmaf(ov.y, wv.y, a1);
      a2 = fmaf(ov.z, wv.z, a2);
      a3 = fmaf(ov.w, wv.w, a3);
    }
    lg[tid] = (a0 + a1) + (a2 + a3);
  }
  __syncthreads();
  if (tid < 64) {
    float v0 = lg[tid];
    float v1 = (tid + 64 < C) ? lg[tid + 64] : -3.0e38f;
    float m = fmaxf(v0, v1);
#pragma unroll
    for (int off = 32; off > 0; off >>= 1) m = fmaxf(m, __shfl_xor(m, off, 64));
    float e0 = __expf(v0 - m);
    float e1 = (tid + 64 < C) ? __expf(v1 - m) : 0.f;
    float ssum = e0 + e1;
#pragma unroll
    for (int off = 32; off > 0; off >>= 1) ssum += __shfl_xor(ssum, off, 64);
    float inv = 1.f / ssum;
    dout[(size_t)b * C + tid] = e0 * inv;
    if (tid + 64 < C) dout[(size_t)b * C + tid + 64] = e1 * inv;
  }
}

// ---------------------------------------------------------------------------
extern "C" void kernel_launch(void* const* d_in, const int* in_sizes, int n_in,
                              void* d_out, int out_size, void* d_ws, size_t ws_size,
                              hipStream_t stream) {
  (void)in_sizes; (void)n_in; (void)out_size;
  const float* x = (const float*)d_in[0];
  const float* Wx = (const float*)d_in[1];
  const float* Wh = (const float*)d_in[2];
  const float* W1 = (const float*)d_in[3];
  const float* W2 = (const float*)d_in[4];
  const float* W3 = (const float*)d_in[5];
  float* ws = (float*)d_ws;

  // runtime k-split for fc1 based on workspace size (psum = KS*256*512 floats)
  const int KS = (ws_size >= 70ull * 1024 * 1024) ? 64 : 32;
  const int KCH = K1 / KS;

  const size_t gx_f = (size_t)B * SCHUNK * G;          // 6,291,456
  const size_t psum_f = (size_t)KS * B * N1;           // 8.39M (KS=64) / 4.19M (KS=32)
  const size_t region0 = (psum_f > gx_f) ? psum_f : gx_f;

  float* gx = ws;            // region0 (dead before fc1)
  float* psum = ws;          // overlays gx
  unsigned short* gouth = (unsigned short*)(ws + region0);
  unsigned short* goutl = gouth + (size_t)B * K1;
  float* out1 = (float*)(goutl + (size_t)B * K1);
  float* hst = out1 + (size_t)B * N1;

  for (int sc = 0; sc < NCHUNK; sc++) {
    k_gemm_gx<<<dim3(B), dim3(256), 0, stream>>>(x, Wx, gx, sc);
    k_scan<<<dim3(B), dim3(256), 0, stream>>>(gx, Wh, gouth, goutl, hst, sc);
  }
  k_fc1<<<dim3(4 * KS), dim3(256), 0, stream>>>(gouth, goutl, W1, psum, KCH);
  k_red<<<dim3(128), dim3(256), 0, stream>>>(psum, out1, KS);
  k_tail<<<dim3(B), dim3(256), 0, stream>>>(out1, W2, W3, (float*)d_out);
}

// Round 3
// 488.871 us; speedup vs baseline: 1.7571x; 1.2897x over previous
//
#include <hip/hip_runtime.h>

// ---------------------------------------------------------------------------
// GRU (B=256,S=512,F=128,H=64) + MLP(32768->512->256->100) + softmax.
// Round 3:
//   k_convW   : W_x2h fp32 -> bf16 hi/lo planes (once, tiny).
//   k_gemm_gx : split-bf16 3-pass MFMA GEMM (x hi/lo in-kernel) -> gx fp32.
//   k_scan    : 4-wave quad-k-split scan; DPP quad_perm reduce (no ds_swizzle),
//               double-buffered h_s -> ONE barrier/step, depth-2 gx prefetch.
//   k_fc1     : 3-pass split-bf16 MFMA GEMM -> psum (k-split, no atomics).
//   k_red     : psum reduction -> out1.
//   k_tail    : relu -> FC2 -> relu -> FC3 -> softmax -> d_out.
// ---------------------------------------------------------------------------

constexpr int B = 256, S = 512, F = 128, H = 64, G = 192, C = 100;
constexpr int N1 = 512;
constexpr int SCHUNK = 128, NCHUNK = 4;
constexpr int K1 = S * H;  // 32768

typedef __attribute__((ext_vector_type(8))) __bf16 bf16x8;
typedef __attribute__((ext_vector_type(4))) float f32x4;

__device__ __forceinline__ unsigned short f2bf(float f) {
  unsigned int u = __float_as_uint(f);
  unsigned int r = (u + 0x7FFFu + ((u >> 16) & 1u)) >> 16;
  return (unsigned short)r;
}
__device__ __forceinline__ float bf2f(unsigned short s) {
  return __uint_as_float((unsigned int)s << 16);
}
__device__ __forceinline__ float sigm_fast(float x) {
  float e = __builtin_amdgcn_exp2f(-1.4426950408889634f * x);
  return __builtin_amdgcn_rcpf(1.f + e);
}
__device__ __forceinline__ float tanh_fast(float x) {
  float e = __builtin_amdgcn_exp2f(2.8853900817779268f * x);  // e^{2x}
  return 1.f - 2.f * __builtin_amdgcn_rcpf(1.f + e);
}
// sum over the 4 lanes of a quad (lanes 4j..4j+3) via DPP quad_perm adds
__device__ __forceinline__ float quad_add(float v) {
  int y = __builtin_amdgcn_update_dpp(0, __float_as_int(v), 0xB1, 0xF, 0xF, true);
  float s = v + __int_as_float(y);
  int z = __builtin_amdgcn_update_dpp(0, __float_as_int(s), 0x4E, 0xF, 0xF, true);
  return s + __int_as_float(z);
}

// ---------------------------------------------------------------------------
// Convert W_x2h (192x128 fp32) to bf16 hi/lo planes (row-major, same layout).
// ---------------------------------------------------------------------------
__global__ void k_convW(const float* __restrict__ Wx, unsigned short* __restrict__ Wh_hi,
                        unsigned short* __restrict__ Wh_lo) {
  int el = blockIdx.x * 256 + threadIdx.x;
  float v = Wx[el];
  unsigned short hi = f2bf(v);
  Wh_hi[el] = hi;
  Wh_lo[el] = f2bf(v - bf2f(hi));
}

// ---------------------------------------------------------------------------
// GEMM1 (MFMA): gx[b][sl][g] = sum_f x[b, sc*128+sl, f] * Wx[g][f]
// One block per batch b: tile 128(M) x 192(N), K=128, BK=32, waves 2x2
// (wave tile 64x96). x converted to bf16 hi/lo in-kernel; Wx from planes.
// 3-pass split-bf16: Ah*Bh + Al*Bh + Ah*Bl. Slot swizzle sq = cq ^ (row&3).
// ---------------------------------------------------------------------------
__global__ __launch_bounds__(256, 1) void k_gemm_gx(const float* __restrict__ x,
                                                    const unsigned short* __restrict__ Whp,
                                                    const unsigned short* __restrict__ Wlp,
                                                    float* __restrict__ gx, int sc) {
  __shared__ unsigned short Ah[128 * 32];
  __shared__ unsigned short Al[128 * 32];
  __shared__ unsigned short Bh[192 * 32];
  __shared__ unsigned short Bl[192 * 32];
  const int t = threadIdx.x;
  const int b = blockIdx.x;
  const int w = t >> 6, l = t & 63;
  const int wm = w >> 1, wn = w & 1;
  const float* arow = x + ((size_t)b * S + (size_t)sc * SCHUNK) * F;

  f32x4 acc[4][6] = {};

  const int ar_ = t >> 1, ahh = t & 1;  // A staging: 2 threads/row
  for (int kc = 0; kc < 4; kc++) {
    const int k0 = kc * 32;
    // ---- stage A: load fp32 x, split hi/lo ----
    {
      const float* sp = arow + (size_t)ar_ * F + k0 + ahh * 16;
      float fv[16];
#pragma unroll
      for (int c = 0; c < 4; c++) {
        float4 v = *(const float4*)(sp + c * 4);
        fv[c * 4 + 0] = v.x; fv[c * 4 + 1] = v.y; fv[c * 4 + 2] = v.z; fv[c * 4 + 3] = v.w;
      }
      unsigned short hi[16], lo[16];
#pragma unroll
      for (int e = 0; e < 16; e++) {
        hi[e] = f2bf(fv[e]);
        lo[e] = f2bf(fv[e] - bf2f(hi[e]));
      }
#pragma unroll
      for (int half = 0; half < 2; half++) {
        int cq = ahh * 2 + half;
        int sq = cq ^ (ar_ & 3);
        unsigned short* dh = &Ah[ar_ * 32 + sq * 8];
        unsigned short* dl = &Al[ar_ * 32 + sq * 8];
#pragma unroll
        for (int e = 0; e < 8; e++) {
          dh[e] = hi[half * 8 + e];
          dl[e] = lo[half * 8 + e];
        }
      }
    }
    // ---- stage B: pure copy from pre-converted planes ----
    if (t < 192) {
#pragma unroll
      for (int cq = 0; cq < 4; cq++) {
        int sq = cq ^ (t & 3);
        *(uint4*)&Bh[t * 32 + sq * 8] = *(const uint4*)(Whp + (size_t)t * F + k0 + cq * 8);
        *(uint4*)&Bl[t * 32 + sq * 8] = *(const uint4*)(Wlp + (size_t)t * F + k0 + cq * 8);
      }
    }
    __syncthreads();
    // ---- fragments + MFMA ----
    bf16x8 bhf[6], blf[6];
#pragma unroll
    for (int nf = 0; nf < 6; nf++) {
      int rowb = wn * 96 + nf * 16 + (l & 15);
      int sq = (l >> 4) ^ (rowb & 3);
      bhf[nf] = *(const bf16x8*)&Bh[rowb * 32 + sq * 8];
      blf[nf] = *(const bf16x8*)&Bl[rowb * 32 + sq * 8];
    }
#pragma unroll
    for (int mf = 0; mf < 4; mf++) {
      int rowa = wm * 64 + mf * 16 + (l & 15);
      int sq = (l >> 4) ^ (rowa & 3);
      bf16x8 ah = *(const bf16x8*)&Ah[rowa * 32 + sq * 8];
      bf16x8 al = *(const bf16x8*)&Al[rowa * 32 + sq * 8];
#pragma unroll
      for (int nf = 0; nf < 6; nf++) {
        acc[mf][nf] = __builtin_amdgcn_mfma_f32_16x16x32_bf16(ah, bhf[nf], acc[mf][nf], 0, 0, 0);
        acc[mf][nf] = __builtin_amdgcn_mfma_f32_16x16x32_bf16(al, bhf[nf], acc[mf][nf], 0, 0, 0);
        acc[mf][nf] = __builtin_amdgcn_mfma_f32_16x16x32_bf16(ah, blf[nf], acc[mf][nf], 0, 0, 0);
      }
    }
    __syncthreads();
  }
  // ---- store: D row=(l>>4)*4+r (x row sl), col=l&15 (g) ----
#pragma unroll
  for (int mf = 0; mf < 4; mf++) {
#pragma unroll
    for (int nf = 0; nf < 6; nf++) {
      int m = wm * 64 + mf * 16 + (l >> 4) * 4;
      int n = wn * 96 + nf * 16 + (l & 15);
      float* dst = gx + ((size_t)b * SCHUNK + m) * G + n;
#pragma unroll
      for (int r = 0; r < 4; r++) dst[(size_t)r * G] = acc[mf][nf][r];
    }
  }
}

// ---------------------------------------------------------------------------
// GRU scan v3: 256 threads (4 waves). Thread (w,l): output j=16w+(l>>2),
// k-slice q=l&3 (16 k each; lanes of a quad = one j). DPP quad_perm reduce,
// double-buffered h_s -> one barrier per step, depth-2 gx prefetch.
// ---------------------------------------------------------------------------
__global__ __launch_bounds__(256, 1) void k_scan(const float* __restrict__ gx,
                                                 const float* __restrict__ Wh,
                                                 unsigned short* __restrict__ outh,
                                                 unsigned short* __restrict__ outl,
                                                 float* __restrict__ hst, int sc) {
  __shared__ float h_s[2][64];
  const int t = threadIdx.x;
  const int w = t >> 6, l = t & 63;
  const int j = (w << 4) | (l >> 2);
  const int q = l & 3;
  const int b = blockIdx.x;

  float Wr[16], Wi[16], Wn[16];
  {
    const float* p0 = Wh + (size_t)j * H + q * 16;
    const float* p1 = Wh + (size_t)(64 + j) * H + q * 16;
    const float* p2 = Wh + (size_t)(128 + j) * H + q * 16;
#pragma unroll
    for (int c = 0; c < 4; c++) {
      float4 v0 = *(const float4*)(p0 + c * 4);
      float4 v1 = *(const float4*)(p1 + c * 4);
      float4 v2 = *(const float4*)(p2 + c * 4);
      Wr[c * 4 + 0] = v0.x; Wr[c * 4 + 1] = v0.y; Wr[c * 4 + 2] = v0.z; Wr[c * 4 + 3] = v0.w;
      Wi[c * 4 + 0] = v1.x; Wi[c * 4 + 1] = v1.y; Wi[c * 4 + 2] = v1.z; Wi[c * 4 + 3] = v1.w;
      Wn[c * 4 + 0] = v2.x; Wn[c * 4 + 1] = v2.y; Wn[c * 4 + 2] = v2.z; Wn[c * 4 + 3] = v2.w;
    }
  }
  float h_own;
  if (sc == 0) {
    h_own = 0.f;
    if (t < 64) h_s[0][t] = 0.f;
  } else {
    h_own = hst[b * H + j];
    if (t < 64) h_s[0][t] = hst[b * H + t];
  }
  asm volatile("s_waitcnt lgkmcnt(0)\n\ts_barrier" ::: "memory");

  const float* gxb = gx + (size_t)b * SCHUNK * G;
  float gr0 = gxb[j], gi0 = gxb[64 + j], gn0 = gxb[128 + j];
  float gr1 = gxb[G + j], gi1 = gxb[G + 64 + j], gn1 = gxb[G + 128 + j];
  unsigned short* poh = outh + (size_t)b * K1 + (size_t)sc * SCHUNK * H + j;
  unsigned short* pol = outl + (size_t)b * K1 + (size_t)sc * SCHUNK * H + j;

  int cur = 0;
  for (int sl = 0; sl < SCHUNK; sl++) {
    const float* hb = &h_s[cur][q * 16];
    float4 ha = *(const float4*)(hb);
    float4 hc = *(const float4*)(hb + 4);
    float4 hd = *(const float4*)(hb + 8);
    float4 he = *(const float4*)(hb + 12);
    int pf = (sl + 2 < SCHUNK) ? sl + 2 : SCHUNK - 1;
    const float* gp = gxb + (size_t)pf * G;
    float grn = gp[j], gin = gp[64 + j], gnn = gp[128 + j];

    float ar, ai, an;
    ar = Wr[0] * ha.x; ai = Wi[0] * ha.x; an = Wn[0] * ha.x;
    ar = fmaf(Wr[1], ha.y, ar); ai = fmaf(Wi[1], ha.y, ai); an = fmaf(Wn[1], ha.y, an);
    ar = fmaf(Wr[2], ha.z, ar); ai = fmaf(Wi[2], ha.z, ai); an = fmaf(Wn[2], ha.z, an);
    ar = fmaf(Wr[3], ha.w, ar); ai = fmaf(Wi[3], ha.w, ai); an = fmaf(Wn[3], ha.w, an);
    ar = fmaf(Wr[4], hc.x, ar); ai = fmaf(Wi[4], hc.x, ai); an = fmaf(Wn[4], hc.x, an);
    ar = fmaf(Wr[5], hc.y, ar); ai = fmaf(Wi[5], hc.y, ai); an = fmaf(Wn[5], hc.y, an);
    ar = fmaf(Wr[6], hc.z, ar); ai = fmaf(Wi[6], hc.z, ai); an = fmaf(Wn[6], hc.z, an);
    ar = fmaf(Wr[7], hc.w, ar); ai = fmaf(Wi[7], hc.w, ai); an = fmaf(Wn[7], hc.w, an);
    ar = fmaf(Wr[8], hd.x, ar); ai = fmaf(Wi[8], hd.x, ai); an = fmaf(Wn[8], hd.x, an);
    ar = fmaf(Wr[9], hd.y, ar); ai = fmaf(Wi[9], hd.y, ai); an = fmaf(Wn[9], hd.y, an);
    ar = fmaf(Wr[10], hd.z, ar); ai = fmaf(Wi[10], hd.z, ai); an = fmaf(Wn[10], hd.z, an);
    ar = fmaf(Wr[11], hd.w, ar); ai = fmaf(Wi[11], hd.w, ai); an = fmaf(Wn[11], hd.w, an);
    ar = fmaf(Wr[12], he.x, ar); ai = fmaf(Wi[12], he.x, ai); an = fmaf(Wn[12], he.x, an);
    ar = fmaf(Wr[13], he.y, ar); ai = fmaf(Wi[13], he.y, ai); an = fmaf(Wn[13], he.y, an);
    ar = fmaf(Wr[14], he.z, ar); ai = fmaf(Wi[14], he.z, ai); an = fmaf(Wn[14], he.z, an);
    ar = fmaf(Wr[15], he.w, ar); ai = fmaf(Wi[15], he.w, ai); an = fmaf(Wn[15], he.w, an);

    ar = quad_add(ar);
    ai = quad_add(ai);
    an = quad_add(an);

    float rr = sigm_fast(ar + gr0);
    float ii = sigm_fast(ai + gi0);
    float na = gn0 + rr * an;
    float th = tanh_fast(na);
    h_own = th + ii * (h_own - th);

    int nxt = cur ^ 1;
    if (q == 0) {
      h_s[nxt][j] = h_own;
      unsigned short hh2 = f2bf(h_own);
      poh[(size_t)sl * H] = hh2;
      pol[(size_t)sl * H] = f2bf(h_own - bf2f(hh2));
    }
    gr0 = gr1; gi0 = gi1; gn0 = gn1;
    gr1 = grn; gi1 = gin; gn1 = gnn;
    // single barrier: write of h_s[nxt] visible; everyone done reading h_s[cur]
    asm volatile("s_waitcnt lgkmcnt(0)\n\ts_barrier" ::: "memory");
    cur = nxt;
  }
  if (q == 0) hst[b * H + j] = h_own;
}

// ---------------------------------------------------------------------------
// FC1 (MFMA): psum[ks][m][n] = sum_{k in chunk ks} A[m][k]*W1[n][k]
// A given as bf16 hi/lo planes; W1 converted in-kernel. 3-pass split-bf16.
// ---------------------------------------------------------------------------
__global__ __launch_bounds__(256, 1) void k_fc1(const unsigned short* __restrict__ Ahp,
                                                const unsigned short* __restrict__ Alp,
                                                const float* __restrict__ W1,
                                                float* __restrict__ psum, int KCH) {
  __shared__ unsigned short Ah[256 * 32];
  __shared__ unsigned short Al[256 * 32];
  __shared__ unsigned short Bh[128 * 32];
  __shared__ unsigned short Bl[128 * 32];
  const int t = threadIdx.x;
  const int ntile = blockIdx.x & 3;
  const int ks = blockIdx.x >> 2;
  const int k0b = ks * KCH;
  const int w = t >> 6, l = t & 63;
  const int wm = w >> 1, wn = w & 1;

  f32x4 acc[8][4] = {};

  const int br = t >> 1, bhh = t & 1;
  const float* bsrc = W1 + (size_t)(ntile * 128 + br) * K1 + bhh * 16;
  const int nkc = KCH >> 5;

  for (int kc = 0; kc < nkc; kc++) {
    const int k0 = k0b + kc * 32;
#pragma unroll
    for (int i = 0; i < 4; i++) {
      int slot = t + i * 256;
      int row = slot >> 2, sq = slot & 3;
      int cq = sq ^ (row & 3);
      const uint4* sh = (const uint4*)(Ahp + (size_t)row * K1 + k0 + cq * 8);
      const uint4* sl2 = (const uint4*)(Alp + (size_t)row * K1 + k0 + cq * 8);
      *(uint4*)&Ah[row * 32 + sq * 8] = *sh;
      *(uint4*)&Al[row * 32 + sq * 8] = *sl2;
    }
    {
      const float* sp = bsrc + k0;
      float fv[16];
#pragma unroll
      for (int c = 0; c < 4; c++) {
        float4 v = *(const float4*)(sp + c * 4);
        fv[c * 4 + 0] = v.x; fv[c * 4 + 1] = v.y; fv[c * 4 + 2] = v.z; fv[c * 4 + 3] = v.w;
      }
      unsigned short hi[16], lo[16];
#pragma unroll
      for (int e = 0; e < 16; e++) {
        hi[e] = f2bf(fv[e]);
        lo[e] = f2bf(fv[e] - bf2f(hi[e]));
      }
#pragma unroll
      for (int half = 0; half < 2; half++) {
        int cq = bhh * 2 + half;
        int sq = cq ^ (br & 3);
        unsigned short* dh = &Bh[br * 32 + sq * 8];
        unsigned short* dl = &Bl[br * 32 + sq * 8];
#pragma unroll
        for (int e = 0; e < 8; e++) {
          dh[e] = hi[half * 8 + e];
          dl[e] = lo[half * 8 + e];
        }
      }
    }
    __syncthreads();
    bf16x8 bhf[4], blf[4];
#pragma unroll
    for (int nf = 0; nf < 4; nf++) {
      int rowb = wn * 64 + nf * 16 + (l & 15);
      int sq = (l >> 4) ^ (rowb & 3);
      bhf[nf] = *(const bf16x8*)&Bh[rowb * 32 + sq * 8];
      blf[nf] = *(const bf16x8*)&Bl[rowb * 32 + sq * 8];
    }
#pragma unroll
    for (int mf = 0; mf < 8; mf++) {
      int rowa = wm * 128 + mf * 16 + (l & 15);
      int sq = (l >> 4) ^ (rowa & 3);
      bf16x8 ah = *(const bf16x8*)&Ah[rowa * 32 + sq * 8];
      bf16x8 al = *(const bf16x8*)&Al[rowa * 32 + sq * 8];
#pragma unroll
      for (int nf = 0; nf < 4; nf++) {
        acc[mf][nf] = __builtin_amdgcn_mfma_f32_16x16x32_bf16(ah, bhf[nf], acc[mf][nf], 0, 0, 0);
        acc[mf][nf] = __builtin_amdgcn_mfma_f32_16x16x32_bf16(al, bhf[nf], acc[mf][nf], 0, 0, 0);
        acc[mf][nf] = __builtin_amdgcn_mfma_f32_16x16x32_bf16(ah, blf[nf], acc[mf][nf], 0, 0, 0);
      }
    }
    __syncthreads();
  }
#pragma unroll
  for (int mf = 0; mf < 8; mf++) {
#pragma unroll
    for (int nf = 0; nf < 4; nf++) {
      int m = wm * 128 + mf * 16 + (l >> 4) * 4;
      int n = ntile * 128 + wn * 64 + nf * 16 + (l & 15);
      float* dst = psum + ((size_t)ks * 256 + m) * N1 + n;
#pragma unroll
      for (int r = 0; r < 4; r++) dst[(size_t)r * N1] = acc[mf][nf][r];
    }
  }
}

// ---------------------------------------------------------------------------
__global__ void k_red(const float* __restrict__ psum, float* __restrict__ out1, int KS) {
  int i = (blockIdx.x * 256 + threadIdx.x) * 4;
  float4 s = make_float4(0.f, 0.f, 0.f, 0.f);
  for (int ks = 0; ks < KS; ks++) {
    float4 v = *(const float4*)(psum + (size_t)ks * (B * N1) + i);
    s.x += v.x; s.y += v.y; s.z += v.z; s.w += v.w;
  }
  *(float4*)(out1 + i) = s;
}

// ---------------------------------------------------------------------------
__global__ __launch_bounds__(256, 1) void k_tail(const float* __restrict__ out1,
                                                 const float* __restrict__ W2,
                                                 const float* __restrict__ W3,
                                                 float* __restrict__ dout) {
  __shared__ float o1[N1];
  __shared__ float o2[256];
  __shared__ float lg[128];
  const int tid = threadIdx.x;
  const int b = blockIdx.x;
  {
    float2 v = *(const float2*)(out1 + (size_t)b * N1 + tid * 2);
    o1[tid * 2 + 0] = fmaxf(v.x, 0.f);
    o1[tid * 2 + 1] = fmaxf(v.y, 0.f);
  }
  __syncthreads();
  {
    const float* w2r = W2 + (size_t)tid * N1;
    float a0 = 0, a1 = 0, a2 = 0, a3 = 0;
#pragma unroll 4
    for (int k = 0; k < N1; k += 4) {
      float4 ov = *(const float4*)(o1 + k);
      float4 wv = *(const float4*)(w2r + k);
      a0 = fmaf(ov.x, wv.x, a0);
      a1 = fmaf(ov.y, wv.y, a1);
      a2 = fmaf(ov.z, wv.z, a2);
      a3 = fmaf(ov.w, wv.w, a3);
    }
    o2[tid] = fmaxf((a0 + a1) + (a2 + a3), 0.f);
  }
  __syncthreads();
  if (tid < C) {
    const float* w3r = W3 + (size_t)tid * 256;
    float a0 = 0, a1 = 0, a2 = 0, a3 = 0;
#pragma unroll 4
    for (int k = 0; k < 256; k += 4) {
      float4 ov = *(const float4*)(o2 + k);
      float4 wv = *(const float4*)(w3r + k);
      a0 = fmaf(ov.x, wv.x, a0);
      a1 = fmaf(ov.y, wv.y, a1);
      a2 = fmaf(ov.z, wv.z, a2);
      a3 = fmaf(ov.w, wv.w, a3);
    }
    lg[tid] = (a0 + a1) + (a2 + a3);
  }
  __syncthreads();
  if (tid < 64) {
    float v0 = lg[tid];
    float v1 = (tid + 64 < C) ? lg[tid + 64] : -3.0e38f;
    float m = fmaxf(v0, v1);
#pragma unroll
    for (int off = 32; off > 0; off >>= 1) m = fmaxf(m, __shfl_xor(m, off, 64));
    float e0 = __expf(v0 - m);
    float e1 = (tid + 64 < C) ? __expf(v1 - m) : 0.f;
    float ssum = e0 + e1;
#pragma unroll
    for (int off = 32; off > 0; off >>= 1) ssum += __shfl_xor(ssum, off, 64);
    float inv = 1.f / ssum;
    dout[(size_t)b * C + tid] = e0 * inv;
    if (tid + 64 < C) dout[(size_t)b * C + tid + 64] = e1 * inv;
  }
}

// ---------------------------------------------------------------------------
extern "C" void kernel_launch(void* const* d_in, const int* in_sizes, int n_in,
                              void* d_out, int out_size, void* d_ws, size_t ws_size,
                              hipStream_t stream) {
  (void)in_sizes; (void)n_in; (void)out_size;
  const float* x = (const float*)d_in[0];
  const float* Wx = (const float*)d_in[1];
  const float* Wh = (const float*)d_in[2];
  const float* W1 = (const float*)d_in[3];
  const float* W2 = (const float*)d_in[4];
  const float* W3 = (const float*)d_in[5];
  float* ws = (float*)d_ws;

  const int KS = (ws_size >= 110ull * 1024 * 1024) ? 64 : 32;
  const int KCH = K1 / KS;

  const size_t gx_f = (size_t)B * SCHUNK * G;   // 6.29M floats
  const size_t psum_f = (size_t)KS * B * N1;    // 8.39M (KS=64) / 4.19M (KS=32)
  const size_t region0 = (psum_f > gx_f) ? psum_f : gx_f;

  float* gx = ws;    // region0 (dead before fc1)
  float* psum = ws;  // overlays gx
  unsigned short* gouth = (unsigned short*)(ws + region0);
  unsigned short* goutl = gouth + (size_t)B * K1;
  float* out1 = (float*)(goutl + (size_t)B * K1);
  float* hst = out1 + (size_t)B * N1;
  unsigned short* Wxh = (unsigned short*)(hst + (size_t)B * H);
  unsigned short* Wxl = Wxh + (size_t)G * F;

  k_convW<<<dim3((G * F) / 256), dim3(256), 0, stream>>>(Wx, Wxh, Wxl);
  for (int sc = 0; sc < NCHUNK; sc++) {
    k_gemm_gx<<<dim3(B), dim3(256), 0, stream>>>(x, Wxh, Wxl, gx, sc);
    k_scan<<<dim3(B), dim3(256), 0, stream>>>(gx, Wh, gouth, goutl, hst, sc);
  }
  k_fc1<<<dim3(4 * KS), dim3(256), 0, stream>>>(gouth, goutl, W1, psum, KCH);
  k_red<<<dim3(128), dim3(256), 0, stream>>>(psum, out1, KS);
  k_tail<<<dim3(B), dim3(256), 0, stream>>>(out1, W2, W3, (float*)d_out);
}

// Round 4
// 423.571 us; speedup vs baseline: 2.0280x; 1.1542x over previous
//
#include <hip/hip_runtime.h>

// ---------------------------------------------------------------------------
// GRU (B=256,S=512,F=128,H=64) + MLP(32768->512->256->100) + softmax.
// Round 4:
//   k_convW : W_x2h fp32 -> bf16 hi/lo planes (once, tiny).
//   k_fused : ONE kernel, 1 block = 1 batch. Per S-chunk of 128:
//               gemm (split-bf16 MFMA, A/B frags loaded direct from global,
//               D -> gx in LDS) then 128-step scan (DPP quad reduce, dbuf h,
//               single raw barrier/step, gx prefetched from LDS).
//             Emits h as bf16 hi/lo planes for fc1.
//   k_fc1   : 3-pass split-bf16 MFMA GEMM, 512 thr/block, 64-way k-split,
//             fp32 atomicAdd into out1 (no psum/reduce).
//   k_tail  : relu -> FC2 -> relu -> FC3 -> softmax -> d_out.
// ---------------------------------------------------------------------------

constexpr int B = 256, S = 512, F = 128, H = 64, G = 192, C = 100;
constexpr int N1 = 512;
constexpr int SCHUNK = 128, NCHUNK = 4;
constexpr int K1 = S * H;  // 32768

typedef __attribute__((ext_vector_type(8))) __bf16 bf16x8;
typedef __attribute__((ext_vector_type(8))) short s16x8;
typedef __attribute__((ext_vector_type(4))) float f32x4;

union BFU {
  s16x8 s;
  bf16x8 b;
};

__device__ __forceinline__ unsigned short f2bf(float f) {
  unsigned int u = __float_as_uint(f);
  unsigned int r = (u + 0x7FFFu + ((u >> 16) & 1u)) >> 16;
  return (unsigned short)r;
}
__device__ __forceinline__ float bf2f(unsigned short s) {
  return __uint_as_float((unsigned int)s << 16);
}
__device__ __forceinline__ float sigm_fast(float x) {
  float e = __builtin_amdgcn_exp2f(-1.4426950408889634f * x);
  return __builtin_amdgcn_rcpf(1.f + e);
}
__device__ __forceinline__ float tanh_fast(float x) {
  float e = __builtin_amdgcn_exp2f(2.8853900817779268f * x);  // e^{2x}
  return 1.f - 2.f * __builtin_amdgcn_rcpf(1.f + e);
}
// sum over the 4 lanes of a quad via DPP quad_perm butterflies
__device__ __forceinline__ float quad_add(float v) {
  int y = __builtin_amdgcn_update_dpp(0, __float_as_int(v), 0xB1, 0xF, 0xF, true);
  float s = v + __int_as_float(y);
  int z = __builtin_amdgcn_update_dpp(0, __float_as_int(s), 0x4E, 0xF, 0xF, true);
  return s + __int_as_float(z);
}

// ---------------------------------------------------------------------------
__global__ void k_convW(const float* __restrict__ Wx, unsigned short* __restrict__ Wh_hi,
                        unsigned short* __restrict__ Wh_lo) {
  int el = blockIdx.x * 256 + threadIdx.x;
  float v = Wx[el];
  unsigned short hi = f2bf(v);
  Wh_hi[el] = hi;
  Wh_lo[el] = f2bf(v - bf2f(hi));
}

// ---------------------------------------------------------------------------
// Fused gemm_gx + GRU scan. 256 blocks (one batch each), 256 threads (4 waves).
// ---------------------------------------------------------------------------
__global__ __launch_bounds__(256, 1) void k_fused(const float* __restrict__ x,
                                                  const unsigned short* __restrict__ Whp,
                                                  const unsigned short* __restrict__ Wlp,
                                                  const float* __restrict__ Wh,
                                                  unsigned short* __restrict__ outh,
                                                  unsigned short* __restrict__ outl) {
  __shared__ float gxl[SCHUNK * G];  // 96 KB: gx chunk [sl][g]
  __shared__ float h_s[2][64];
  const int t = threadIdx.x;
  const int w = t >> 6, l = t & 63;
  const int b = blockIdx.x;
  // gemm wave layout (2x2 waves, wave tile 64m x 96n)
  const int wm = w >> 1, wn = w & 1;
  const int lm = l & 15, lk = l >> 4;
  // scan layout: output col j, k-slice q
  const int j = (w << 4) | (l >> 2);
  const int q = l & 3;

  // W_h2h rows resident in VGPRs for the whole kernel
  float Wr[16], Wi[16], Wn_[16];
  {
    const float* p0 = Wh + (size_t)j * H + q * 16;
    const float* p1 = Wh + (size_t)(64 + j) * H + q * 16;
    const float* p2 = Wh + (size_t)(128 + j) * H + q * 16;
#pragma unroll
    for (int c = 0; c < 4; c++) {
      float4 v0 = *(const float4*)(p0 + c * 4);
      float4 v1 = *(const float4*)(p1 + c * 4);
      float4 v2 = *(const float4*)(p2 + c * 4);
      Wr[c * 4 + 0] = v0.x; Wr[c * 4 + 1] = v0.y; Wr[c * 4 + 2] = v0.z; Wr[c * 4 + 3] = v0.w;
      Wi[c * 4 + 0] = v1.x; Wi[c * 4 + 1] = v1.y; Wi[c * 4 + 2] = v1.z; Wi[c * 4 + 3] = v1.w;
      Wn_[c * 4 + 0] = v2.x; Wn_[c * 4 + 1] = v2.y; Wn_[c * 4 + 2] = v2.z; Wn_[c * 4 + 3] = v2.w;
    }
  }
  float h_own = 0.f;
  if (t < 64) h_s[0][t] = 0.f;
  int cur = 0;
  __syncthreads();

  unsigned short* poh_b = outh + (size_t)b * K1 + j;
  unsigned short* pol_b = outl + (size_t)b * K1 + j;

  for (int sc = 0; sc < NCHUNK; sc++) {
    const float* arow = x + ((size_t)b * S + (size_t)sc * SCHUNK) * F;
    // ================= GEMM phase: gx = x_chunk @ Wx^T (split-bf16 3-pass) ==
    f32x4 acc[4][6] = {};
#pragma unroll
    for (int kc = 0; kc < 4; kc++) {
      const int k0 = kc * 32;
      bf16x8 bhf[6], blf[6];
#pragma unroll
      for (int nf = 0; nf < 6; nf++) {
        int g = wn * 96 + nf * 16 + lm;
        bhf[nf] = *(const bf16x8*)(Whp + (size_t)g * F + k0 + lk * 8);
        blf[nf] = *(const bf16x8*)(Wlp + (size_t)g * F + k0 + lk * 8);
      }
#pragma unroll
      for (int mf = 0; mf < 4; mf++) {
        int rowa = wm * 64 + mf * 16 + lm;
        const float* ap = arow + (size_t)rowa * F + k0 + lk * 8;
        float4 a0 = *(const float4*)(ap);
        float4 a1 = *(const float4*)(ap + 4);
        float av[8] = {a0.x, a0.y, a0.z, a0.w, a1.x, a1.y, a1.z, a1.w};
        BFU ah, al;
#pragma unroll
        for (int e = 0; e < 8; e++) {
          unsigned short hi = f2bf(av[e]);
          ah.s[e] = (short)hi;
          al.s[e] = (short)f2bf(av[e] - bf2f(hi));
        }
#pragma unroll
        for (int nf = 0; nf < 6; nf++) {
          acc[mf][nf] = __builtin_amdgcn_mfma_f32_16x16x32_bf16(ah.b, bhf[nf], acc[mf][nf], 0, 0, 0);
          acc[mf][nf] = __builtin_amdgcn_mfma_f32_16x16x32_bf16(al.b, bhf[nf], acc[mf][nf], 0, 0, 0);
          acc[mf][nf] = __builtin_amdgcn_mfma_f32_16x16x32_bf16(ah.b, blf[nf], acc[mf][nf], 0, 0, 0);
        }
      }
    }
    // D -> LDS gx  (previous scan's reads all completed at its final barrier)
#pragma unroll
    for (int mf = 0; mf < 4; mf++)
#pragma unroll
      for (int nf = 0; nf < 6; nf++) {
        int m = wm * 64 + mf * 16 + lk * 4;
        int n = wn * 96 + nf * 16 + lm;
#pragma unroll
        for (int r = 0; r < 4; r++) gxl[(m + r) * G + n] = acc[mf][nf][r];
      }
    __syncthreads();

    // ================= SCAN phase: 128 steps ===============================
    float gr = gxl[j], gi = gxl[64 + j], gn = gxl[128 + j];
    for (int sl = 0; sl < SCHUNK; sl++) {
      const float* hb = &h_s[cur][q * 16];
      float4 ha = *(const float4*)(hb);
      float4 hc = *(const float4*)(hb + 4);
      float4 hd = *(const float4*)(hb + 8);
      float4 he = *(const float4*)(hb + 12);
      int np = (sl + 1) & (SCHUNK - 1);  // last iter reads row 0, discarded
      float grn = gxl[np * G + j];
      float gin = gxl[np * G + 64 + j];
      float gnn = gxl[np * G + 128 + j];

      float ar, ai, an;
      ar = Wr[0] * ha.x; ai = Wi[0] * ha.x; an = Wn_[0] * ha.x;
      ar = fmaf(Wr[1], ha.y, ar); ai = fmaf(Wi[1], ha.y, ai); an = fmaf(Wn_[1], ha.y, an);
      ar = fmaf(Wr[2], ha.z, ar); ai = fmaf(Wi[2], ha.z, ai); an = fmaf(Wn_[2], ha.z, an);
      ar = fmaf(Wr[3], ha.w, ar); ai = fmaf(Wi[3], ha.w, ai); an = fmaf(Wn_[3], ha.w, an);
      ar = fmaf(Wr[4], hc.x, ar); ai = fmaf(Wi[4], hc.x, ai); an = fmaf(Wn_[4], hc.x, an);
      ar = fmaf(Wr[5], hc.y, ar); ai = fmaf(Wi[5], hc.y, ai); an = fmaf(Wn_[5], hc.y, an);
      ar = fmaf(Wr[6], hc.z, ar); ai = fmaf(Wi[6], hc.z, ai); an = fmaf(Wn_[6], hc.z, an);
      ar = fmaf(Wr[7], hc.w, ar); ai = fmaf(Wi[7], hc.w, ai); an = fmaf(Wn_[7], hc.w, an);
      ar = fmaf(Wr[8], hd.x, ar); ai = fmaf(Wi[8], hd.x, ai); an = fmaf(Wn_[8], hd.x, an);
      ar = fmaf(Wr[9], hd.y, ar); ai = fmaf(Wi[9], hd.y, ai); an = fmaf(Wn_[9], hd.y, an);
      ar = fmaf(Wr[10], hd.z, ar); ai = fmaf(Wi[10], hd.z, ai); an = fmaf(Wn_[10], hd.z, an);
      ar = fmaf(Wr[11], hd.w, ar); ai = fmaf(Wi[11], hd.w, ai); an = fmaf(Wn_[11], hd.w, an);
      ar = fmaf(Wr[12], he.x, ar); ai = fmaf(Wi[12], he.x, ai); an = fmaf(Wn_[12], he.x, an);
      ar = fmaf(Wr[13], he.y, ar); ai = fmaf(Wi[13], he.y, ai); an = fmaf(Wn_[13], he.y, an);
      ar = fmaf(Wr[14], he.z, ar); ai = fmaf(Wi[14], he.z, ai); an = fmaf(Wn_[14], he.z, an);
      ar = fmaf(Wr[15], he.w, ar); ai = fmaf(Wi[15], he.w, ai); an = fmaf(Wn_[15], he.w, an);

      ar = quad_add(ar);
      ai = quad_add(ai);
      an = quad_add(an);

      float rr = sigm_fast(ar + gr);
      float ii = sigm_fast(ai + gi);
      float na = gn + rr * an;
      float th = tanh_fast(na);
      h_own = th + ii * (h_own - th);

      int nxt = cur ^ 1;
      if (q == 0) {
        h_s[nxt][j] = h_own;
        unsigned short hh = f2bf(h_own);
        size_t so = (size_t)(sc * SCHUNK + sl) * H;
        poh_b[so] = hh;
        pol_b[so] = f2bf(h_own - bf2f(hh));
      }
      gr = grn; gi = gin; gn = gnn;
      // single barrier: h_s[nxt] write visible; everyone done with h_s[cur]
      asm volatile("s_waitcnt lgkmcnt(0)\n\ts_barrier" ::: "memory");
      cur = nxt;
    }
  }
}

// ---------------------------------------------------------------------------
// FC1 (MFMA): out1[m][n] += sum_k A[m][k]*W1[n][k]; 3-pass split-bf16.
// 512 threads (8 waves, 4x2), tile M=256 x N=128, BK=32, 64-way k-split,
// fp32 atomicAdd accumulation. XCD-bijective block remap.
// ---------------------------------------------------------------------------
__global__ __launch_bounds__(512, 1) void k_fc1(const unsigned short* __restrict__ Ahp,
                                                const unsigned short* __restrict__ Alp,
                                                const float* __restrict__ W1,
                                                float* __restrict__ out1) {
  __shared__ unsigned short Ah[256 * 32];  // 16 KB
  __shared__ unsigned short Al[256 * 32];
  __shared__ unsigned short Bh[128 * 32];  // 8 KB
  __shared__ unsigned short Bl[128 * 32];
  const int t = threadIdx.x;
  const int bid = blockIdx.x;
  const int v = (bid & 7) * 32 + (bid >> 3);  // XCD-contiguous virtual id
  const int ks = v >> 2, ntile = v & 3;       // 4 ntile-sharers on same XCD
  const int k0b = ks * 512;
  const int w = t >> 6, l = t & 63;
  const int wm = w >> 1, wn = w & 1;  // 4x2 waves, wave tile 64m x 64n
  const int lm = l & 15, lk = l >> 4;

  f32x4 acc[4][4] = {};
  const int br = t >> 2, qt = t & 3;  // B staging: 4 threads/row

  for (int kc = 0; kc < 16; kc++) {
    const int k0 = k0b + kc * 32;
    // ---- stage A hi/lo (pure copy, slot swizzle sq = cq ^ (row&3)) ----
#pragma unroll
    for (int i = 0; i < 2; i++) {
      int slot = t + i * 512;  // 0..1023
      int row = slot >> 2, sq = slot & 3;
      int cq = sq ^ (row & 3);
      *(uint4*)&Ah[row * 32 + sq * 8] = *(const uint4*)(Ahp + (size_t)row * K1 + k0 + cq * 8);
      *(uint4*)&Al[row * 32 + sq * 8] = *(const uint4*)(Alp + (size_t)row * K1 + k0 + cq * 8);
    }
    // ---- stage B: load fp32 W1, split hi/lo, packed writes ----
    {
      const float* sp = W1 + (size_t)(ntile * 128 + br) * K1 + k0 + qt * 8;
      float4 v0 = *(const float4*)(sp);
      float4 v1 = *(const float4*)(sp + 4);
      float fv[8] = {v0.x, v0.y, v0.z, v0.w, v1.x, v1.y, v1.z, v1.w};
      unsigned int hp[4], lp[4];
#pragma unroll
      for (int e = 0; e < 4; e++) {
        unsigned short h0 = f2bf(fv[2 * e]), h1 = f2bf(fv[2 * e + 1]);
        unsigned short l0 = f2bf(fv[2 * e] - bf2f(h0));
        unsigned short l1 = f2bf(fv[2 * e + 1] - bf2f(h1));
        hp[e] = (unsigned int)h0 | ((unsigned int)h1 << 16);
        lp[e] = (unsigned int)l0 | ((unsigned int)l1 << 16);
      }
      int sq = qt ^ (br & 3);
      *(uint4*)&Bh[br * 32 + sq * 8] = make_uint4(hp[0], hp[1], hp[2], hp[3]);
      *(uint4*)&Bl[br * 32 + sq * 8] = make_uint4(lp[0], lp[1], lp[2], lp[3]);
    }
    __syncthreads();
    // ---- fragments + MFMA (3 passes) ----
    bf16x8 bhf[4], blf[4];
#pragma unroll
    for (int nf = 0; nf < 4; nf++) {
      int rowb = wn * 64 + nf * 16 + lm;
      int sq = lk ^ (rowb & 3);
      bhf[nf] = *(const bf16x8*)&Bh[rowb * 32 + sq * 8];
      blf[nf] = *(const bf16x8*)&Bl[rowb * 32 + sq * 8];
    }
#pragma unroll
    for (int mf = 0; mf < 4; mf++) {
      int rowa = wm * 64 + mf * 16 + lm;
      int sq = lk ^ (rowa & 3);
      bf16x8 ah = *(const bf16x8*)&Ah[rowa * 32 + sq * 8];
      bf16x8 al = *(const bf16x8*)&Al[rowa * 32 + sq * 8];
#pragma unroll
      for (int nf = 0; nf < 4; nf++) {
        acc[mf][nf] = __builtin_amdgcn_mfma_f32_16x16x32_bf16(ah, bhf[nf], acc[mf][nf], 0, 0, 0);
        acc[mf][nf] = __builtin_amdgcn_mfma_f32_16x16x32_bf16(al, bhf[nf], acc[mf][nf], 0, 0, 0);
        acc[mf][nf] = __builtin_amdgcn_mfma_f32_16x16x32_bf16(ah, blf[nf], acc[mf][nf], 0, 0, 0);
      }
    }
    __syncthreads();
  }
  // ---- atomic accumulate into out1 ----
#pragma unroll
  for (int mf = 0; mf < 4; mf++)
#pragma unroll
    for (int nf = 0; nf < 4; nf++) {
      int m = wm * 64 + mf * 16 + lk * 4;
      int n = ntile * 128 + wn * 64 + nf * 16 + lm;
#pragma unroll
      for (int r = 0; r < 4; r++)
        atomicAdd(out1 + (size_t)(m + r) * N1 + n, acc[mf][nf][r]);
    }
}

// ---------------------------------------------------------------------------
__global__ __launch_bounds__(256, 1) void k_tail(const float* __restrict__ out1,
                                                 const float* __restrict__ W2,
                                                 const float* __restrict__ W3,
                                                 float* __restrict__ dout) {
  __shared__ float o1[N1];
  __shared__ float o2[256];
  __shared__ float lg[128];
  const int tid = threadIdx.x;
  const int b = blockIdx.x;
  {
    float2 v = *(const float2*)(out1 + (size_t)b * N1 + tid * 2);
    o1[tid * 2 + 0] = fmaxf(v.x, 0.f);
    o1[tid * 2 + 1] = fmaxf(v.y, 0.f);
  }
  __syncthreads();
  {
    const float* w2r = W2 + (size_t)tid * N1;
    float a0 = 0, a1 = 0, a2 = 0, a3 = 0;
#pragma unroll 4
    for (int k = 0; k < N1; k += 4) {
      float4 ov = *(const float4*)(o1 + k);
      float4 wv = *(const float4*)(w2r + k);
      a0 = fmaf(ov.x, wv.x, a0);
      a1 = fmaf(ov.y, wv.y, a1);
      a2 = fmaf(ov.z, wv.z, a2);
      a3 = fmaf(ov.w, wv.w, a3);
    }
    o2[tid] = fmaxf((a0 + a1) + (a2 + a3), 0.f);
  }
  __syncthreads();
  if (tid < C) {
    const float* w3r = W3 + (size_t)tid * 256;
    float a0 = 0, a1 = 0, a2 = 0, a3 = 0;
#pragma unroll 4
    for (int k = 0; k < 256; k += 4) {
      float4 ov = *(const float4*)(o2 + k);
      float4 wv = *(const float4*)(w3r + k);
      a0 = fmaf(ov.x, wv.x, a0);
      a1 = fmaf(ov.y, wv.y, a1);
      a2 = fmaf(ov.z, wv.z, a2);
      a3 = fmaf(ov.w, wv.w, a3);
    }
    lg[tid] = (a0 + a1) + (a2 + a3);
  }
  __syncthreads();
  if (tid < 64) {
    float v0 = lg[tid];
    float v1 = (tid + 64 < C) ? lg[tid + 64] : -3.0e38f;
    float m = fmaxf(v0, v1);
#pragma unroll
    for (int off = 32; off > 0; off >>= 1) m = fmaxf(m, __shfl_xor(m, off, 64));
    float e0 = __expf(v0 - m);
    float e1 = (tid + 64 < C) ? __expf(v1 - m) : 0.f;
    float ssum = e0 + e1;
#pragma unroll
    for (int off = 32; off > 0; off >>= 1) ssum += __shfl_xor(ssum, off, 64);
    float inv = 1.f / ssum;
    dout[(size_t)b * C + tid] = e0 * inv;
    if (tid + 64 < C) dout[(size_t)b * C + tid + 64] = e1 * inv;
  }
}

// ---------------------------------------------------------------------------
extern "C" void kernel_launch(void* const* d_in, const int* in_sizes, int n_in,
                              void* d_out, int out_size, void* d_ws, size_t ws_size,
                              hipStream_t stream) {
  (void)in_sizes; (void)n_in; (void)out_size; (void)ws_size;
  const float* x = (const float*)d_in[0];
  const float* Wx = (const float*)d_in[1];
  const float* Wh = (const float*)d_in[2];
  const float* W1 = (const float*)d_in[3];
  const float* W2 = (const float*)d_in[4];
  const float* W3 = (const float*)d_in[5];

  // ws layout (all 16B-aligned): Wx planes, out planes, out1.  ~34.2 MB total.
  unsigned short* Wxh = (unsigned short*)d_ws;
  unsigned short* Wxl = Wxh + (size_t)G * F;
  unsigned short* gouth = Wxl + (size_t)G * F;
  unsigned short* goutl = gouth + (size_t)B * K1;
  float* out1 = (float*)(goutl + (size_t)B * K1);

  hipMemsetAsync(out1, 0, (size_t)B * N1 * sizeof(float), stream);
  k_convW<<<dim3((G * F) / 256), dim3(256), 0, stream>>>(Wx, Wxh, Wxl);
  k_fused<<<dim3(B), dim3(256), 0, stream>>>(x, Wxh, Wxl, Wh, gouth, goutl);
  k_fc1<<<dim3(256), dim3(512), 0, stream>>>(gouth, goutl, W1, out1);
  k_tail<<<dim3(B), dim3(256), 0, stream>>>(out1, W2, W3, (float*)d_out);
}